// Round 4
// baseline (392.748 us; speedup 1.0000x reference)
//
#include <hip/hip_runtime.h>

#define CC   1024
#define C2   2048
#define HH   64
#define WW   64
#define HW   4096
#define MOUT 2048
#define NB   4

typedef short  short8  __attribute__((ext_vector_type(8)));
typedef float  floatx4 __attribute__((ext_vector_type(4)));

static __device__ __forceinline__ unsigned short f2bf(float f) {
  unsigned int u = __builtin_bit_cast(unsigned int, f);
  u = u + 0x7FFFu + ((u >> 16) & 1u);   // RNE truncate to bf16
  return (unsigned short)(u >> 16);
}

// async 16B global -> LDS (DMA: wave-uniform LDS base + lane*16)
static __device__ __forceinline__ void glds16(const unsigned short* g, unsigned short* l) {
  __builtin_amdgcn_global_load_lds(
      (const __attribute__((address_space(1))) void*)g,
      (__attribute__((address_space(3))) void*)l, 16, 0, 0);
}

// ---------------------------------------------------------------------------
// Kernel 1: 3x3 conv (2048 -> 2 ch), SAME pad. R6 structure (unchanged).
// ---------------------------------------------------------------------------
__global__ __launch_bounds__(256)
void conv_off(const float* __restrict__ refer, const float* __restrict__ sup,
              const float* __restrict__ woff, float* __restrict__ off)
{
  const int cz = blockIdx.x;             // channel chunk: 32 channels
  const int ry = blockIdx.y;             // row tile: 8 rows
  const int b  = blockIdx.z;
  const int wv = threadIdx.x >> 6;       // wave 0..3 -> 2 rows each
  const int w  = threadIdx.x & 63;       // column
  const int h0 = ry * 8 + wv * 2;

  const int cc0 = cz * 32;               // global input-channel base
  const float* basep = (cz < 32)
      ? refer + ((size_t)b * CC + cc0) * HW
      : sup   + ((size_t)b * CC + (cc0 - CC)) * HW;

  const int gy0 = h0 - 1;
  const bool top_ok = (gy0 >= 0);
  const bool bot_ok = (h0 + 2 < HH);

  float a00 = 0.f, a01 = 0.f, a10 = 0.f, a11 = 0.f;

  float rn[4];
#pragma unroll
  for (int j = 0; j < 4; j++) {
    const bool ok = (j == 0) ? top_ok : (j == 3) ? bot_ok : true;
    rn[j] = ok ? basep[(gy0 + j) * WW + w] : 0.f;
  }

  for (int ci = 0; ci < 32; ci++) {
    float rc[4];
#pragma unroll
    for (int j = 0; j < 4; j++) rc[j] = rn[j];

    if (ci < 31) {
      const float* pn = basep + (size_t)(ci + 1) * HW;
#pragma unroll
      for (int j = 0; j < 4; j++) {
        const bool ok = (j == 0) ? top_ok : (j == 3) ? bot_ok : true;
        rn[j] = ok ? pn[(gy0 + j) * WW + w] : 0.f;
      }
    }

    float lft[4], rgt[4];
#pragma unroll
    for (int j = 0; j < 4; j++) {
      const float tl = __shfl(rc[j], (w - 1) & 63, 64);
      const float tr = __shfl(rc[j], (w + 1) & 63, 64);
      lft[j] = (w == 0)  ? 0.f : tl;
      rgt[j] = (w == 63) ? 0.f : tr;
    }

    const int cc = cc0 + ci;
    const float* wp0 = woff + (size_t)cc * 9;          // o=0 (dy)
    const float* wp1 = woff + (size_t)(C2 + cc) * 9;   // o=1 (dx)
#pragma unroll
    for (int ky = 0; ky < 3; ky++) {
      const float w00 = wp0[ky * 3 + 0], w01 = wp0[ky * 3 + 1], w02 = wp0[ky * 3 + 2];
      const float w10 = wp1[ky * 3 + 0], w11 = wp1[ky * 3 + 1], w12 = wp1[ky * 3 + 2];
      a00 += lft[ky]     * w00 + rc[ky]     * w01 + rgt[ky]     * w02;
      a01 += lft[ky]     * w10 + rc[ky]     * w11 + rgt[ky]     * w12;
      a10 += lft[ky + 1] * w00 + rc[ky + 1] * w01 + rgt[ky + 1] * w02;
      a11 += lft[ky + 1] * w10 + rc[ky + 1] * w11 + rgt[ky + 1] * w12;
    }
  }

  atomicAdd(&off[((b * 2 + 0) * HH + h0) * WW + w],     a00);
  atomicAdd(&off[((b * 2 + 1) * HH + h0) * WW + w],     a01);
  atomicAdd(&off[((b * 2 + 0) * HH + h0 + 1) * WW + w], a10);
  atomicAdd(&off[((b * 2 + 1) * HH + h0 + 1) * WW + w], a11);
}

// ---------------------------------------------------------------------------
// Kernel 2: fp32 -> bf16 convert for w_def (unchanged)
// ---------------------------------------------------------------------------
__global__ __launch_bounds__(256)
void cvt_bf16(const float* __restrict__ src, unsigned short* __restrict__ dst, int n4)
{
  const int i = blockIdx.x * 256 + threadIdx.x;
  if (i < n4) {
    const float4 f = ((const float4*)src)[i];
    ushort4 u;
    u.x = f2bf(f.x); u.y = f2bf(f.y); u.z = f2bf(f.z); u.w = f2bf(f.w);
    ((ushort4*)dst)[i] = u;
  }
}

// ---------------------------------------------------------------------------
// Kernel 3: bilinear deform-sample (r5 VERIFIED, unchanged).
// ---------------------------------------------------------------------------
__global__ __launch_bounds__(256)
void sample_kern(const float* __restrict__ sup, const float* __restrict__ off,
                 const float* __restrict__ boff, unsigned short* __restrict__ St)
{
  const int h   = blockIdx.x;
  const int ct  = blockIdx.y;
  const int b   = blockIdx.z;
  const int tid = threadIdx.x;

  __shared__ float swy[64], swx[64];
  __shared__ int   sy0[64], sx0[64];
  __shared__ unsigned short tile[64 * 68];

  if (tid < 64) {
    const float dy = off[((b * 2 + 0) * HH + h) * WW + tid] + boff[0];
    const float dx = off[((b * 2 + 1) * HH + h) * WW + tid] + boff[1];
    const float py = dy + (float)h;
    const float px = dx + (float)tid;
    const float y0f = floorf(py), x0f = floorf(px);
    sy0[tid] = (int)y0f;  sx0[tid] = (int)x0f;
    swy[tid] = py - y0f;  swx[tid] = px - x0f;
  }
  __syncthreads();

  const int l   = tid & 63;
  const int cs0 = tid >> 6;
  const int y0 = sy0[l], x0 = sx0[l];
  const int y1 = y0 + 1, x1 = x0 + 1;
  const float wy1 = swy[l], wx1 = swx[l];
  const float wy0 = 1.f - wy1, wx0 = 1.f - wx1;
  const float vy0 = (y0 >= 0 && y0 < HH) ? 1.f : 0.f;
  const float vy1 = (y1 >= 0 && y1 < HH) ? 1.f : 0.f;
  const float vx0 = (x0 >= 0 && x0 < WW) ? 1.f : 0.f;
  const float vx1 = (x1 >= 0 && x1 < WW) ? 1.f : 0.f;
  const int cy0 = min(max(y0, 0), HH - 1), cy1 = min(max(y1, 0), HH - 1);
  const int cx0 = min(max(x0, 0), WW - 1), cx1 = min(max(x1, 0), WW - 1);
  const int i00 = cy0 * WW + cx0, i01 = cy0 * WW + cx1;
  const int i10 = cy1 * WW + cx0, i11 = cy1 * WW + cx1;
  const float w00 = wy0 * wx0 * vy0 * vx0;
  const float w01 = wy0 * wx1 * vy0 * vx1;
  const float w10 = wy1 * wx0 * vy1 * vx0;
  const float w11 = wy1 * wx1 * vy1 * vx1;

  const int cb = ct * 64;
  for (int cs = cs0; cs < 64; cs += 4) {
    const float* sp = sup + ((size_t)b * CC + cb + cs) * HW;
    const float v = w00 * sp[i00] + w01 * sp[i01] + w10 * sp[i10] + w11 * sp[i11];
    tile[cs * 68 + l] = f2bf(v);
  }
  __syncthreads();
  const int cq  = tid & 15;
  const int ls0 = tid >> 4;
  unsigned short* stb = St + ((size_t)b * HW + h * 64) * CC;
  for (int ls = ls0; ls < 64; ls += 16) {
    ushort4 pk;
    pk.x = tile[(cq * 4 + 0) * 68 + ls];
    pk.y = tile[(cq * 4 + 1) * 68 + ls];
    pk.z = tile[(cq * 4 + 2) * 68 + ls];
    pk.w = tile[(cq * 4 + 3) * 68 + ls];
    *(ushort4*)&stb[(size_t)ls * CC + cb + cq * 4] = pk;
  }
}

// ---------------------------------------------------------------------------
// Kernel 4 (r10): 128x256 tile (M x N), BK=32, 4 waves (256 thr), 3-buffer
// rotation, ONE barrier + ONE counted vmcnt(6) per K-tile. 72 KB LDS ->
// 2 blocks/CU co-resident (the r7-r9 256^2 configs were 1 block/CU with
// 8 lockstep waves; both pipes <35% util -> convoy/latency-bound, so the
// lever is cross-block TLP, not finer intra-block phases). Wave-tile
// 64x128 keeps the same operand-reuse (22.9 B/KFLOP) as 256^2.
//
// Race-freedom (3-buffer): tile t reads buf[t%3]; stage of tile t+2
// targets buf[(t+2)%3] = buf[(t-1)%3], issued after tile t-1's closing
// barrier, which follows every wave's (lgkm-complete) reads of t-1.
// Reads of tile t follow tile t-1's {vmcnt(6); barrier}: outstanding <=6
// = tile t+1's loads -> tile t's 6 loads retired for all waves. QED.
// Ascending-tile accumulation, same fragment mapping -> bit-identical C.
// ---------------------------------------------------------------------------
#define STAGE_A(s, kk) do { \
  glds16(gA + (kk),                   &lA[s][(wave * 16) * 32]); \
  glds16(gA + (size_t)64 * CC + (kk), &lA[s][(64 + wave * 16) * 32]); \
} while (0)
#define STAGE_B(s, kk) do { \
  glds16(gB + (kk),                    &lB[s][(wave * 16) * 32]); \
  glds16(gB + (size_t)64 * CC + (kk),  &lB[s][(64  + wave * 16) * 32]); \
  glds16(gB + (size_t)128 * CC + (kk), &lB[s][(128 + wave * 16) * 32]); \
  glds16(gB + (size_t)192 * CC + (kk), &lB[s][(192 + wave * 16) * 32]); \
} while (0)

// One K-tile: {12 ds_read || 6 glds(stage t+2) -> 32 MFMA -> vmcnt -> bar}
//   VM: 6 = steady, 0 = drain, 99 = none (also skips barrier)
#define TILE(T, CB, SB, ST, VM) do { \
  short8 af[4], bq[8]; \
  _Pragma("unroll") \
  for (int i_ = 0; i_ < 4; i_++) \
    af[i_] = *(const short8*)&lA[CB][(wmA + i_ * 16 + lrow) * 32 + rdo]; \
  _Pragma("unroll") \
  for (int j_ = 0; j_ < 8; j_++) \
    bq[j_] = *(const short8*)&lB[CB][(wnB + j_ * 16 + lrow) * 32 + rdo]; \
  if (ST) { const int k2_ = ((T) + 2) * 32; STAGE_A(SB, k2_); STAGE_B(SB, k2_); } \
  __builtin_amdgcn_s_setprio(1); \
  _Pragma("unroll") \
  for (int i_ = 0; i_ < 4; i_++) \
    _Pragma("unroll") \
    for (int j_ = 0; j_ < 8; j_++) \
      acc[i_][j_] = __builtin_amdgcn_mfma_f32_16x16x32_bf16(af[i_], bq[j_], acc[i_][j_], 0, 0, 0); \
  __builtin_amdgcn_s_setprio(0); \
  if ((VM) == 6)      asm volatile("s_waitcnt vmcnt(6)" ::: "memory"); \
  else if ((VM) == 0) asm volatile("s_waitcnt vmcnt(0)" ::: "memory"); \
  if ((VM) != 99) __builtin_amdgcn_s_barrier(); \
} while (0)

__global__ __launch_bounds__(256, 2)
void gemm_bt128(const unsigned short* __restrict__ A,
                const unsigned short* __restrict__ Bt,
                float* __restrict__ C)
{
  // XCD-aware bijective swizzle (1024 blocks, 1024%8==0). Within an XCD
  // chunk, m-index walks fastest -> the 512 KB B-panel stays L2-resident
  // across 16 consecutive blocks.
  const int slot = blockIdx.x + (blockIdx.y << 4) + (blockIdx.z << 8);
  const int tile = ((slot & 7) << 7) + (slot >> 3);
  const int m0 = (tile & 15) * 128;
  const int n0 = ((tile >> 4) & 15) * 256;
  const int bb = tile >> 8;
  const unsigned short* Bb = Bt + (size_t)bb * HW * CC;
  float* Cb = C + (size_t)bb * (size_t)MOUT * HW;

  __shared__ __align__(16) unsigned short lA[3][128 * 32];   // 24 KB
  __shared__ __align__(16) unsigned short lB[3][256 * 32];   // 48 KB

  const int tid  = threadIdx.x;
  const int wave = tid >> 6;
  const int lane = tid & 63;
  const int wmA  = (wave >> 1) * 64;         // 2 M-waves
  const int wnB  = (wave & 1) * 128;         // 2 N-waves
  const int lrow = lane & 15;
  const int quad = lane >> 4;
  const int rdo  = ((quad ^ ((lrow >> 1) & 3)) << 3);   // swizzled k-chunk (shorts)

  // staging source (pre-swizzled so linear DMA dest lands swizzled content)
  const int srow = tid >> 2;                             // 0..63
  const int schk = (tid & 3) ^ ((tid >> 3) & 3);
  const unsigned short* gA = A  + (size_t)(m0 + srow) * CC + schk * 8;
  const unsigned short* gB = Bb + (size_t)(n0 + srow) * CC + schk * 8;

  // prologue: stage tiles 0,1 (12 loads/wave in flight)
  STAGE_A(0, 0);  STAGE_B(0, 0);
  STAGE_A(1, 32); STAGE_B(1, 32);

  floatx4 acc[4][8];
#pragma unroll
  for (int i = 0; i < 4; i++)
#pragma unroll
    for (int j = 0; j < 8; j++)
      acc[i][j] = (floatx4){0.f, 0.f, 0.f, 0.f};

  asm volatile("s_waitcnt vmcnt(6)" ::: "memory");   // tile 0 landed
  __builtin_amdgcn_s_barrier();

  // main loop: tiles 0..29, staging tiles 2..31
#pragma unroll 1
  for (int t = 0; t < 30; t += 3) {
    TILE(t + 0, 0, 2, 1, 6);
    TILE(t + 1, 1, 0, 1, 6);
    TILE(t + 2, 2, 1, 1, 6);
  }
  TILE(30, 0, 0, 0, 0);    // drain: tile 31 landed
  TILE(31, 1, 0, 0, 99);

  // epilogue: C[m][n]
#pragma unroll
  for (int i = 0; i < 4; i++) {
    const int mbase = m0 + wmA + i * 16 + quad * 4;
#pragma unroll
    for (int j = 0; j < 8; j++) {
      const int n = n0 + wnB + j * 16 + lrow;
      float* cp = Cb + (size_t)mbase * HW + n;
#pragma unroll
      for (int r = 0; r < 4; r++)
        cp[(size_t)r * HW] = acc[i][j][r];
    }
  }
}

// ---------------------------------------------------------------------------
extern "C" void kernel_launch(void* const* d_in, const int* in_sizes, int n_in,
                              void* d_out, int out_size, void* d_ws, size_t ws_size,
                              hipStream_t stream)
{
  const float* refer = (const float*)d_in[0];
  const float* sup   = (const float*)d_in[1];
  const float* woff  = (const float*)d_in[2];
  const float* boff  = (const float*)d_in[3];
  const float* wdef  = (const float*)d_in[4];
  float* out = (float*)d_out;

  // workspace: [offsets 512KB][w_def bf16 4MB][S_t bf16 32MB]
  char* ws = (char*)d_ws;
  float* off            = (float*)ws;
  unsigned short* wdefb = (unsigned short*)(ws + (512u << 10));
  unsigned short* St    = (unsigned short*)(ws + (512u << 10) + (4u << 20));

  hipMemsetAsync(off, 0, (size_t)NB * 2 * HW * sizeof(float), stream);
  conv_off<<<dim3(64, 8, NB), 256, 0, stream>>>(refer, sup, woff, off);
  cvt_bf16<<<dim3((MOUT * CC / 4 + 255) / 256), 256, 0, stream>>>(wdef, wdefb, MOUT * CC / 4);
  sample_kern<<<dim3(HH, 16, NB), 256, 0, stream>>>(sup, off, boff, St);
  gemm_bt128<<<dim3(HW / 256, MOUT / 128, NB), 256, 0, stream>>>(wdefb, St, out);
}

// Round 5
// 382.404 us; speedup vs baseline: 1.0270x; 1.0270x over previous
//
#include <hip/hip_runtime.h>

#define CC   1024
#define C2   2048
#define HH   64
#define WW   64
#define HW   4096
#define MOUT 2048
#define NB   4

typedef short  short8  __attribute__((ext_vector_type(8)));
typedef float  floatx4 __attribute__((ext_vector_type(4)));

static __device__ __forceinline__ unsigned short f2bf(float f) {
  unsigned int u = __builtin_bit_cast(unsigned int, f);
  u = u + 0x7FFFu + ((u >> 16) & 1u);   // RNE truncate to bf16
  return (unsigned short)(u >> 16);
}

// async 16B global -> LDS (DMA: wave-uniform LDS base + lane*16)
static __device__ __forceinline__ void glds16(const unsigned short* g, unsigned short* l) {
  __builtin_amdgcn_global_load_lds(
      (const __attribute__((address_space(1))) void*)g,
      (__attribute__((address_space(3))) void*)l, 16, 0, 0);
}

// ---------------------------------------------------------------------------
// Kernel 1 (r11): 3x3 conv (2048 -> 2 ch), SAME pad. 8 rows per wave
// (loads 10 -> 1.25x row amplification, was 2 rows/4 loads = 2.0x):
// HBM read 268 MB -> 164 MB. 16-channel chunks, grid (128,2,4) = 1024
// blocks -> 4 blocks/CU, 16 waves/CU. Register prefetch pipeline (load
// ci+1's 10 rows while computing ci) as in r6. shfl executed by all
// lanes. atomicAdd reduction into zeroed off buffer (order already
// nondeterministic).
// ---------------------------------------------------------------------------
__global__ __launch_bounds__(256)
void conv_off(const float* __restrict__ refer, const float* __restrict__ sup,
              const float* __restrict__ woff, float* __restrict__ off)
{
  const int cz = blockIdx.x;             // channel chunk: 16 channels
  const int ry = blockIdx.y;             // row tile: 32 rows
  const int b  = blockIdx.z;
  const int wv = threadIdx.x >> 6;       // wave 0..3 -> 8 rows each
  const int w  = threadIdx.x & 63;       // column
  const int h0 = ry * 32 + wv * 8;       // output rows h0..h0+7

  const int cc0 = cz * 16;               // global input-channel base
  const float* basep = (cz < 64)
      ? refer + ((size_t)b * CC + cc0) * HW
      : sup   + ((size_t)b * CC + (cc0 - CC)) * HW;

  const int gy0 = h0 - 1;                // loaded rows gy0 .. gy0+9
  // only j=0 (h0==0) and j=9 (h0+8==HH) can be out of range
  const bool top_ok = (gy0 >= 0);
  const bool bot_ok = (h0 + 8 < HH);

  float acc0[8], acc1[8];
#pragma unroll
  for (int r = 0; r < 8; r++) { acc0[r] = 0.f; acc1[r] = 0.f; }

  // software pipeline: rn holds channel ci's 10 rows entering iteration ci
  float rn[10];
#pragma unroll
  for (int j = 0; j < 10; j++) {
    const bool ok = (j == 0) ? top_ok : (j == 9) ? bot_ok : true;
    rn[j] = ok ? basep[(gy0 + j) * WW + w] : 0.f;
  }

  for (int ci = 0; ci < 16; ci++) {
    float rc[10];
#pragma unroll
    for (int j = 0; j < 10; j++) rc[j] = rn[j];

    if (ci < 15) {
      const float* pn = basep + (size_t)(ci + 1) * HW;
#pragma unroll
      for (int j = 0; j < 10; j++) {
        const bool ok = (j == 0) ? top_ok : (j == 9) ? bot_ok : true;
        rn[j] = ok ? pn[(gy0 + j) * WW + w] : 0.f;
      }
    }

    float lft[10], rgt[10];
#pragma unroll
    for (int j = 0; j < 10; j++) {
      const float tl = __shfl(rc[j], (w - 1) & 63, 64);   // all lanes active
      const float tr = __shfl(rc[j], (w + 1) & 63, 64);
      lft[j] = (w == 0)  ? 0.f : tl;
      rgt[j] = (w == 63) ? 0.f : tr;
    }

    const int cc = cc0 + ci;
    const float* wp0 = woff + (size_t)cc * 9;          // o=0 (dy)
    const float* wp1 = woff + (size_t)(C2 + cc) * 9;   // o=1 (dx)
#pragma unroll
    for (int ky = 0; ky < 3; ky++) {
      const float w00 = wp0[ky * 3 + 0], w01 = wp0[ky * 3 + 1], w02 = wp0[ky * 3 + 2];
      const float w10 = wp1[ky * 3 + 0], w11 = wp1[ky * 3 + 1], w12 = wp1[ky * 3 + 2];
#pragma unroll
      for (int r = 0; r < 8; r++) {
        acc0[r] += lft[r + ky] * w00 + rc[r + ky] * w01 + rgt[r + ky] * w02;
        acc1[r] += lft[r + ky] * w10 + rc[r + ky] * w11 + rgt[r + ky] * w12;
      }
    }
  }

#pragma unroll
  for (int r = 0; r < 8; r++) {
    atomicAdd(&off[((b * 2 + 0) * HH + h0 + r) * WW + w], acc0[r]);
    atomicAdd(&off[((b * 2 + 1) * HH + h0 + r) * WW + w], acc1[r]);
  }
}

// ---------------------------------------------------------------------------
// Kernel 2: fp32 -> bf16 convert for w_def (unchanged)
// ---------------------------------------------------------------------------
__global__ __launch_bounds__(256)
void cvt_bf16(const float* __restrict__ src, unsigned short* __restrict__ dst, int n4)
{
  const int i = blockIdx.x * 256 + threadIdx.x;
  if (i < n4) {
    const float4 f = ((const float4*)src)[i];
    ushort4 u;
    u.x = f2bf(f.x); u.y = f2bf(f.y); u.z = f2bf(f.z); u.w = f2bf(f.w);
    ((ushort4*)dst)[i] = u;
  }
}

// ---------------------------------------------------------------------------
// Kernel 3: bilinear deform-sample (r5 VERIFIED, unchanged).
// ---------------------------------------------------------------------------
__global__ __launch_bounds__(256)
void sample_kern(const float* __restrict__ sup, const float* __restrict__ off,
                 const float* __restrict__ boff, unsigned short* __restrict__ St)
{
  const int h   = blockIdx.x;            // image row
  const int ct  = blockIdx.y;            // channel tile: [ct*64, +64)
  const int b   = blockIdx.z;
  const int tid = threadIdx.x;

  __shared__ float swy[64], swx[64];
  __shared__ int   sy0[64], sx0[64];
  __shared__ unsigned short tile[64 * 68];   // [c][l], pitch 68

  if (tid < 64) {
    const float dy = off[((b * 2 + 0) * HH + h) * WW + tid] + boff[0];
    const float dx = off[((b * 2 + 1) * HH + h) * WW + tid] + boff[1];
    const float py = dy + (float)h;
    const float px = dx + (float)tid;
    const float y0f = floorf(py), x0f = floorf(px);
    sy0[tid] = (int)y0f;  sx0[tid] = (int)x0f;
    swy[tid] = py - y0f;  swx[tid] = px - x0f;
  }
  __syncthreads();

  const int l   = tid & 63;
  const int cs0 = tid >> 6;
  const int y0 = sy0[l], x0 = sx0[l];
  const int y1 = y0 + 1, x1 = x0 + 1;
  const float wy1 = swy[l], wx1 = swx[l];
  const float wy0 = 1.f - wy1, wx0 = 1.f - wx1;
  const float vy0 = (y0 >= 0 && y0 < HH) ? 1.f : 0.f;
  const float vy1 = (y1 >= 0 && y1 < HH) ? 1.f : 0.f;
  const float vx0 = (x0 >= 0 && x0 < WW) ? 1.f : 0.f;
  const float vx1 = (x1 >= 0 && x1 < WW) ? 1.f : 0.f;
  const int cy0 = min(max(y0, 0), HH - 1), cy1 = min(max(y1, 0), HH - 1);
  const int cx0 = min(max(x0, 0), WW - 1), cx1 = min(max(x1, 0), WW - 1);
  const int i00 = cy0 * WW + cx0, i01 = cy0 * WW + cx1;
  const int i10 = cy1 * WW + cx0, i11 = cy1 * WW + cx1;
  const float w00 = wy0 * wx0 * vy0 * vx0;
  const float w01 = wy0 * wx1 * vy0 * vx1;
  const float w10 = wy1 * wx0 * vy1 * vx0;
  const float w11 = wy1 * wx1 * vy1 * vx1;

  const int cb = ct * 64;
  for (int cs = cs0; cs < 64; cs += 4) {
    const float* sp = sup + ((size_t)b * CC + cb + cs) * HW;
    const float v = w00 * sp[i00] + w01 * sp[i01] + w10 * sp[i10] + w11 * sp[i11];
    tile[cs * 68 + l] = f2bf(v);
  }
  __syncthreads();
  const int cq  = tid & 15;
  const int ls0 = tid >> 4;
  unsigned short* stb = St + ((size_t)b * HW + h * 64) * CC;
  for (int ls = ls0; ls < 64; ls += 16) {
    ushort4 pk;
    pk.x = tile[(cq * 4 + 0) * 68 + ls];
    pk.y = tile[(cq * 4 + 1) * 68 + ls];
    pk.z = tile[(cq * 4 + 2) * 68 + ls];
    pk.w = tile[(cq * 4 + 3) * 68 + ls];
    *(ushort4*)&stb[(size_t)ls * CC + cb + cq * 4] = pk;
  }
}

// ---------------------------------------------------------------------------
// Kernel 4: bf16 MFMA GEMM — REVERTED to the r0/r5-verified gemm_bt
// (128x128 tile, BK=64, global_load_lds width=16, XOR-swizzled LDS,
// conflict-free, ~3 blocks/CU). Best-measured config across r0-r10;
// the 256-class pipelined variants (r7-r10) all plateaued at 84-86 us
// vs this kernel's <79 us.
// ---------------------------------------------------------------------------
__global__ __launch_bounds__(256)
void gemm_bt(const unsigned short* __restrict__ A,
             const unsigned short* __restrict__ Bt,
             float* __restrict__ C)
{
  const int bb = blockIdx.z;
  const int n0 = blockIdx.x * 128;
  const int m0 = blockIdx.y * 128;
  const unsigned short* Bb = Bt + (size_t)bb * HW * CC;
  float* Cb = C + (size_t)bb * (size_t)MOUT * HW;

  __shared__ __align__(16) unsigned short lA[128 * 64];   // 16 KB, 128B rows
  __shared__ __align__(16) unsigned short lB[128 * 64];

  const int tid  = threadIdx.x;
  const int wave = tid >> 6;
  const int lane = tid & 63;
  const int wm   = (wave >> 1) * 64;
  const int wn   = (wave & 1) * 64;
  const int lrow = lane & 15;
  const int quad = lane >> 4;

  const int g8 = lane >> 3;
  const int s8 = (lane & 7) ^ g8;
  const unsigned short* gA = A  + (size_t)(m0 + wave * 32 + g8) * CC + s8 * 8;
  const unsigned short* gB = Bb + (size_t)(n0 + wave * 32 + g8) * CC + s8 * 8;

  floatx4 acc[4][4];
#pragma unroll
  for (int i = 0; i < 4; i++)
#pragma unroll
    for (int j = 0; j < 4; j++)
      acc[i][j] = (floatx4){0.f, 0.f, 0.f, 0.f};

  for (int k0 = 0; k0 < CC; k0 += 64) {
    __syncthreads();
#pragma unroll
    for (int q = 0; q < 4; q++) {
      glds16(gA + (size_t)q * 8 * CC + k0, &lA[(wave * 32 + q * 8) * 64]);
      glds16(gB + (size_t)q * 8 * CC + k0, &lB[(wave * 32 + q * 8) * 64]);
    }
    __syncthreads();

#pragma unroll
    for (int ks = 0; ks < 2; ks++) {
      short8 af[4], bfr[4];
#pragma unroll
      for (int t = 0; t < 4; t++) {
        const int sw = ((ks * 4 + quad) ^ (lrow & 7)) * 8;
        af[t]  = *(const short8*)&lA[(wm + t * 16 + lrow) * 64 + sw];
        bfr[t] = *(const short8*)&lB[(wn + t * 16 + lrow) * 64 + sw];
      }
#pragma unroll
      for (int i = 0; i < 4; i++)
#pragma unroll
        for (int j = 0; j < 4; j++)
          acc[i][j] = __builtin_amdgcn_mfma_f32_16x16x32_bf16(af[i], bfr[j], acc[i][j], 0, 0, 0);
    }
  }

#pragma unroll
  for (int i = 0; i < 4; i++) {
    const int mbase = m0 + wm + i * 16 + quad * 4;
#pragma unroll
    for (int j = 0; j < 4; j++) {
      const int n = n0 + wn + j * 16 + lrow;
      float* cp = Cb + (size_t)mbase * HW + n;
#pragma unroll
      for (int r = 0; r < 4; r++)
        cp[(size_t)r * HW] = acc[i][j][r];
    }
  }
}

// ---------------------------------------------------------------------------
extern "C" void kernel_launch(void* const* d_in, const int* in_sizes, int n_in,
                              void* d_out, int out_size, void* d_ws, size_t ws_size,
                              hipStream_t stream)
{
  const float* refer = (const float*)d_in[0];
  const float* sup   = (const float*)d_in[1];
  const float* woff  = (const float*)d_in[2];
  const float* boff  = (const float*)d_in[3];
  const float* wdef  = (const float*)d_in[4];
  float* out = (float*)d_out;

  // workspace: [offsets 512KB][w_def bf16 4MB][S_t bf16 32MB]
  char* ws = (char*)d_ws;
  float* off            = (float*)ws;
  unsigned short* wdefb = (unsigned short*)(ws + (512u << 10));
  unsigned short* St    = (unsigned short*)(ws + (512u << 10) + (4u << 20));

  hipMemsetAsync(off, 0, (size_t)NB * 2 * HW * sizeof(float), stream);
  conv_off<<<dim3(128, 2, NB), 256, 0, stream>>>(refer, sup, woff, off);
  cvt_bf16<<<dim3((MOUT * CC / 4 + 255) / 256), 256, 0, stream>>>(wdef, wdefb, MOUT * CC / 4);
  sample_kern<<<dim3(HH, 16, NB), 256, 0, stream>>>(sup, off, boff, St);
  gemm_bt<<<dim3(HW / 128, MOUT / 128, NB), 256, 0, stream>>>(wdefb, St, out);
}